// Round 4
// baseline (446.008 us; speedup 1.0000x reference)
//
#include <hip/hip_runtime.h>

// ViterbiLoss (CRF forward) on MI355X — v4.
// Meet-in-the-middle split (256 blocks = (batch,dir), each chain <= 127 steps).
// v3 post-mortem: STEP_BARRIER's ::: "memory" clobber made the waitcnt pass
// emit s_waitcnt vmcnt(0) before the barrier EVERY step -> full HBM latency
// (~900 cyc) on the critical path. v4 barrier has NO memory clobber; instead:
//   - barrier asm defines a zero SGPR; s-vector reads are addressed through it
//     (data dependence -> reads stay after the barrier, still ds_read_b128)
//   - s' store is a volatile DS write (volatile store vs volatile asm = ordered)
//   - prefetch: 4 rotating sets of 12 NAMED floats, loads issued for u+3
// LDS carries only the 48-float score vector. No indexed local arrays.

#define NB 128
#define NT 256
#define NK 48
#define NKK (NK * NK)          // 2304
#define TAG_START 46
#define TAG_STOP 47

// lgkmcnt-only barrier; %0 <- 0 creates the data dependence for the s-reads.
#define BARRIER_DEF_ZERO(z) \
  asm volatile("s_mov_b32 %0, 0\n\ts_waitcnt lgkmcnt(0)\n\ts_barrier" : "=s"(z))

#define LD12(v, p, ST) \
  v##0 = (p)[0*(ST)];  v##1 = (p)[1*(ST)];  v##2  = (p)[2*(ST)];  v##3  = (p)[3*(ST)]; \
  v##4 = (p)[4*(ST)];  v##5 = (p)[5*(ST)];  v##6  = (p)[6*(ST)];  v##7  = (p)[7*(ST)]; \
  v##8 = (p)[8*(ST)];  v##9 = (p)[9*(ST)];  v##10 = (p)[10*(ST)]; v##11 = (p)[11*(ST)];

// one scan step: consume buffer `cur` (tile u), reload buffer `nxt` (tile u+3)
#define STEPB(cur, nxt, ST) { \
  int z_; BARRIER_DEF_ZERO(z_); \
  const float* sc_ = &sv[(u + 1) & 1][rb] + z_; \
  float4 s0 = *(const float4*)(sc_);     \
  float4 s1 = *(const float4*)(sc_ + 4); \
  float4 s2 = *(const float4*)(sc_ + 8); \
  { int up_ = u + 3; if (up_ > nsteps) up_ = nsteps; \
    const float* p_ = basep + (long)up_ * dstep; LD12(nxt, p_, ST) } \
  if (((u - 1) & 3) == 0) { \
    float mm = fmaxf(fmaxf(fmaxf(s0.x,s0.y),fmaxf(s0.z,s0.w)), \
                     fmaxf(fmaxf(s1.x,s1.y),fmaxf(s1.z,s1.w))); \
    mm = fmaxf(mm, fmaxf(fmaxf(s2.x,s2.y),fmaxf(s2.z,s2.w))); \
    mm = fmaxf(mm, __shfl_xor(mm, 1, 64)); \
    mm = fmaxf(mm, __shfl_xor(mm, 2, 64)); \
    c += mm; \
    s0.x-=mm; s0.y-=mm; s0.z-=mm; s0.w-=mm; \
    s1.x-=mm; s1.y-=mm; s1.z-=mm; s1.w-=mm; \
    s2.x-=mm; s2.y-=mm; s2.z-=mm; s2.w-=mm; \
  } \
  float acc = (((__expf(cur##0 + s0.x) + __expf(cur##1 + s0.y)) + \
                (__expf(cur##2 + s0.z) + __expf(cur##3 + s0.w))) + \
               ((__expf(cur##4 + s1.x) + __expf(cur##5 + s1.y)) + \
                (__expf(cur##6 + s1.z) + __expf(cur##7 + s1.w)))) + \
              ((__expf(cur##8 + s2.x) + __expf(cur##9 + s2.y)) + \
               (__expf(cur##10 + s2.z) + __expf(cur##11 + s2.w))); \
  acc += __shfl_xor(acc, 1, 64); \
  acc += __shfl_xor(acc, 2, 64); \
  if (store) *(volatile float*)&sv[u & 1][oo] = __logf(acc); \
}

#define CHAIN(ST) { \
  float a0,a1,a2,a3,a4,a5,a6,a7,a8,a9,a10,a11; \
  float b0,b1,b2,b3,b4,b5,b6,b7,b8,b9,b10,b11; \
  float c0,c1,c2,c3,c4,c5,c6,c7,c8,c9,c10,c11; \
  float d0,d1,d2,d3,d4,d5,d6,d7,d8,d9,d10,d11; \
  { const float* p_ = basep + dstep; LD12(a, p_, ST) } \
  { int u_ = (2 > nsteps) ? nsteps : 2; \
    const float* p_ = basep + (long)u_ * dstep; LD12(b, p_, ST) } \
  { int u_ = (3 > nsteps) ? nsteps : 3; \
    const float* p_ = basep + (long)u_ * dstep; LD12(c, p_, ST) } \
  __syncthreads(); \
  int u = 1; \
  for (;;) { \
    STEPB(a, d, ST) if (++u > nsteps) break; \
    STEPB(b, a, ST) if (++u > nsteps) break; \
    STEPB(c, b, ST) if (++u > nsteps) break; \
    STEPB(d, c, ST) if (++u > nsteps) break; \
  } \
}

__global__ __launch_bounds__(256, 1)
void viterbi_chain_kernel(const float* __restrict__ feats,
                          const int* __restrict__ targets,
                          const int* __restrict__ lengths,
                          float* __restrict__ out,
                          float* __restrict__ ws)
{
    const int bu  = blockIdx.x;
    const int b   = bu >> 1;
    const int dir = bu & 1;
    const int tid = threadIdx.x;
    const int len = lengths[b], last = len - 1, m = last >> 1;
    const float* __restrict__ fb = feats + (size_t)b * (NT * NKK);

    __shared__ float sv[2][NK];
    __shared__ float gred[4];

    // ---- gold slice: fwd owns t in [0,m], bwd owns t in [m+1,last] ----
    {
        int tg  = dir ? (m + 1 + tid) : tid;
        int tmx = dir ? last : m;
        float g = 0.f;
        if (tg <= tmx) g = fb[(size_t)tg * NKK + targets[b * NT + tg]];
        #pragma unroll
        for (int o = 32; o; o >>= 1) g += __shfl_down(g, o, 64);
        if ((tid & 63) == 0) gred[tid >> 6] = g;
    }

    // ---- chain init vector ----
    if (tid < NK) {
        float iv;
        if (dir) iv = (last == 0) ? ((tid == TAG_STOP) ? 0.f : -1e30f)
                                  : fb[(size_t)last * NKK + tid * NK + TAG_STOP];
        else     iv = fb[TAG_START * NK + tid];
        sv[0][tid] = iv;
    }

    const int lane = tid & 63, w = tid >> 6, qq = lane & 3, rb = qq * 12;
    const int oo   = w * 12 + (lane >> 2);           // output index (active < 48)
    const int ooc  = (oo < NK) ? oo : (NK - 1);      // clamped for addresses only
    const bool store = ((lane >> 2) < 12) && (qq == 0);

    int nsteps = dir ? (last - 1 - m) : m;
    if (nsteps < 0) nsteps = 0;

    float c = 0.f;
    if (nsteps > 0) {
        if (dir) {  // backward: lane reads row ooc, contiguous 12 -> dwordx4
            const float* basep = fb + (size_t)last * NKK + (size_t)ooc * NK + rb;
            const long dstep = -(long)NKK;
            CHAIN(1)
        } else {    // forward: lane reads column ooc, stride NK
            const float* basep = fb + (size_t)rb * NK + ooc;
            const long dstep = (long)NKK;
            CHAIN(NK)
        }
    } else {
        __syncthreads();
    }

    __syncthreads();   // publish last step's volatile store (full drain, once)

    // ---- emit half-chain result: 48 floats + log-offset at [48] ----
    if (tid < NK) ws[(size_t)bu * 64 + tid] = sv[nsteps & 1][tid];
    if (tid == 0) {
        ws[(size_t)bu * 64 + 48] = c;
        atomicAdd(out, -(gred[0] + gred[1] + gred[2] + gred[3]));
    }
}

__global__ __launch_bounds__(64, 1)
void viterbi_combine_kernel(const float* __restrict__ ws,
                            float* __restrict__ out)
{
    const int b = blockIdx.x, lane = threadIdx.x;
    const float* f = ws + (size_t)(2 * b) * 64;
    const float* g = ws + (size_t)(2 * b + 1) * 64;
    float v = -3.0e38f;
    if (lane < NK) v = f[lane] + g[lane];
    float mm = v;
    #pragma unroll
    for (int o = 32; o; o >>= 1) mm = fmaxf(mm, __shfl_xor(mm, o, 64));
    float e = (lane < NK) ? __expf(v - mm) : 0.f;
    #pragma unroll
    for (int o = 32; o; o >>= 1) e += __shfl_xor(e, o, 64);
    if (lane == 0) atomicAdd(out, __logf(e) + mm + f[NK] + g[NK]);
}

extern "C" void kernel_launch(void* const* d_in, const int* in_sizes, int n_in,
                              void* d_out, int out_size, void* d_ws, size_t ws_size,
                              hipStream_t stream) {
    const float* feats   = (const float*)d_in[0];
    const int*   targets = (const int*)d_in[1];
    const int*   lengths = (const int*)d_in[2];
    float*       out     = (float*)d_out;
    float*       ws      = (float*)d_ws;

    hipMemsetAsync(out, 0, sizeof(float), stream);
    viterbi_chain_kernel<<<dim3(2 * NB), dim3(NT), 0, stream>>>(feats, targets, lengths, out, ws);
    viterbi_combine_kernel<<<dim3(NB), dim3(64), 0, stream>>>(ws, out);
}